// Round 1
// baseline (613.288 us; speedup 1.0000x reference)
//
#include <hip/hip_runtime.h>
#include <hip/hip_bf16.h>

// Problem constants (B=2, C=64, H=W=128)
#define NPIX 16384      // H*W
#define NPOOL 4096      // (H/2)*(W/2)
#define BN 32768        // B*NPIX
#define NCHUNK 4        // M-split for occupancy

// ---------------- K1: theta = conv1x1(x, w_theta) -> Q[B*N][8] ----------------
__global__ __launch_bounds__(256) void theta_kernel(
    const float* __restrict__ x, const float* __restrict__ w,
    const float* __restrict__ bias, float* __restrict__ q) {
  int idx = blockIdx.x * 256 + threadIdx.x;   // 0..BN-1
  int b = idx >> 14, n = idx & (NPIX - 1);
  const float* xb = x + (size_t)b * 64 * NPIX + n;
  float acc[8];
#pragma unroll
  for (int j = 0; j < 8; j++) acc[j] = bias[j];
  for (int c = 0; c < 64; c++) {
    float xv = xb[(size_t)c * NPIX];          // coalesced across threads
#pragma unroll
    for (int j = 0; j < 8; j++) acc[j] += xv * w[j * 64 + c];  // scalar loads
  }
  float* qo = q + (size_t)idx * 8;
#pragma unroll
  for (int j = 0; j < 8; j++) qo[j] = acc[j];
}

// ------- K2: phiT[B][M][8], g[B][M][64] = maxpool2(conv1x1(x, w)) --------
// one block per (batch, pooled row); stages 2 pixel rows x 64 ch in LDS
__global__ __launch_bounds__(256) void pool_kernel(
    const float* __restrict__ x,
    const float* __restrict__ w_phi, const float* __restrict__ b_phi,
    const float* __restrict__ w_g, const float* __restrict__ b_g,
    float* __restrict__ phiT, float* __restrict__ g) {
  __shared__ float xs[64][256];               // 64 KB
  int bid = blockIdx.x;
  int b = bid >> 6, pr = bid & 63;            // pooled row 0..63
  const float* xb = x + (size_t)b * 64 * NPIX + pr * 256;
  int t = threadIdx.x;
  for (int c = 0; c < 64; c++) xs[c][t] = xb[(size_t)c * NPIX + t];
  __syncthreads();
  // 72 output channels (64 g + 8 phi) x 64 pooled positions = 4608 outputs
#pragma unroll 1
  for (int iter = 0; iter < 18; iter++) {
    int out_i = iter * 256 + t;
    int oc = out_i >> 6;                      // wave-uniform
    int pos = out_i & 63;
    const float* wrow;
    float bv;
    if (oc < 64) { wrow = w_g + oc * 64; bv = b_g[oc]; }
    else         { wrow = w_phi + (oc - 64) * 64; bv = b_phi[oc - 64]; }
    float a0 = bv, a1 = bv, a2 = bv, a3 = bv;
    int p0 = pos * 2;
    for (int c = 0; c < 64; c++) {
      float wv = wrow[c];                     // scalar load (oc wave-uniform)
      a0 += wv * xs[c][p0];
      a1 += wv * xs[c][p0 + 1];
      a2 += wv * xs[c][p0 + 128];
      a3 += wv * xs[c][p0 + 129];
    }
    float v = fmaxf(fmaxf(a0, a1), fmaxf(a2, a3));
    int m = pr * 64 + pos;
    if (oc < 64) g[(((size_t)b * NPOOL) + m) * 64 + oc] = v;
    else         phiT[(((size_t)b * NPOOL) + m) * 8 + (oc - 64)] = v;
  }
}

// ---------------- K3: flash attention partials (no-max softmax) ----------------
// grid (128, NCHUNK): blockIdx.x = b*64 + qtile (256 queries), blockIdx.y = M-chunk
__global__ __launch_bounds__(256) void attn_kernel(
    const float* __restrict__ q, const float* __restrict__ phiT,
    const float* __restrict__ g, float* __restrict__ part_l,
    float* __restrict__ part_o) {
  __shared__ float phis[128][8];              // 4 KB
  __shared__ float gs[128][64];               // 32 KB
  int qblk = blockIdx.x;
  int chunk = blockIdx.y;
  int t = threadIdx.x;
  int qi = qblk * 256 + t;                    // global query 0..BN-1
  int b = qblk >> 6;
  float4 q0 = *(const float4*)(q + (size_t)qi * 8);
  float4 q1 = *(const float4*)(q + (size_t)qi * 8 + 4);
  float o[64];
#pragma unroll
  for (int c = 0; c < 64; c++) o[c] = 0.f;
  float l = 0.f;
  int kbase = b * NPOOL + chunk * (NPOOL / NCHUNK);
  for (int m0 = 0; m0 < NPOOL / NCHUNK; m0 += 128) {
    // stage 128 keys: phi rows (contiguous 4KB) + g rows (contiguous 32KB)
    const float4* psrc = (const float4*)(phiT + (size_t)(kbase + m0) * 8);
    ((float4*)phis)[t] = psrc[t];
    const float4* gsrc = (const float4*)(g + (size_t)(kbase + m0) * 64);
#pragma unroll
    for (int i = 0; i < 8; i++) ((float4*)gs)[t + 256 * i] = gsrc[t + 256 * i];
    __syncthreads();
    for (int k = 0; k < 128; k++) {
      float4 p0 = *(const float4*)&phis[k][0];   // broadcast: conflict-free
      float4 p1 = *(const float4*)&phis[k][4];
      float s = q0.x * p0.x + q0.y * p0.y + q0.z * p0.z + q0.w * p0.w +
                q1.x * p1.x + q1.y * p1.y + q1.z * p1.z + q1.w * p1.w;
      float p = __expf(fminf(s, 60.f));          // inf-guard; data max ~20
      l += p;
#pragma unroll
      for (int cc = 0; cc < 16; cc++) {
        float4 gv = *(const float4*)&gs[k][cc * 4];  // broadcast
        o[cc * 4 + 0] += p * gv.x;
        o[cc * 4 + 1] += p * gv.y;
        o[cc * 4 + 2] += p * gv.z;
        o[cc * 4 + 3] += p * gv.w;
      }
    }
    __syncthreads();
  }
  size_t pbase = (size_t)chunk * BN + qi;
  part_l[pbase] = l;
  float* po = part_o + pbase * 64;
#pragma unroll
  for (int cc = 0; cc < 16; cc++)
    *(float4*)(po + cc * 4) =
        make_float4(o[cc * 4], o[cc * 4 + 1], o[cc * 4 + 2], o[cc * 4 + 3]);
}

// ---------------- K4: combine partials + epilogue ----------------
__global__ __launch_bounds__(256) void reduce_kernel(
    const float* __restrict__ part_l, const float* __restrict__ part_o,
    const float* __restrict__ x, const float* __restrict__ sig,
    float* __restrict__ out) {
  int qi = blockIdx.x * 256 + threadIdx.x;    // 0..BN-1
  float l = 0.f;
#pragma unroll
  for (int ch = 0; ch < NCHUNK; ch++) l += part_l[(size_t)ch * BN + qi];
  float o[64];
#pragma unroll
  for (int c = 0; c < 64; c++) o[c] = 0.f;
#pragma unroll
  for (int ch = 0; ch < NCHUNK; ch++) {
    const float* po = part_o + ((size_t)ch * BN + qi) * 64;
#pragma unroll
    for (int cc = 0; cc < 16; cc++) {
      float4 v = *(const float4*)(po + cc * 4);
      o[cc * 4 + 0] += v.x;
      o[cc * 4 + 1] += v.y;
      o[cc * 4 + 2] += v.z;
      o[cc * 4 + 3] += v.w;
    }
  }
  float scale = sig[0] / l;
  int b = qi >> 14, n = qi & (NPIX - 1);
  const float* xb = x + (size_t)b * 64 * NPIX + n;
  float* ob = out + (size_t)b * 64 * NPIX + n;
#pragma unroll
  for (int c = 0; c < 64; c++)
    ob[(size_t)c * NPIX] = xb[(size_t)c * NPIX] + o[c] * scale;
}

extern "C" void kernel_launch(void* const* d_in, const int* in_sizes, int n_in,
                              void* d_out, int out_size, void* d_ws, size_t ws_size,
                              hipStream_t stream) {
  const float* x       = (const float*)d_in[0];
  const float* w_theta = (const float*)d_in[1];
  const float* b_theta = (const float*)d_in[2];
  const float* w_phi   = (const float*)d_in[3];
  const float* b_phi   = (const float*)d_in[4];
  const float* w_g     = (const float*)d_in[5];
  const float* b_g     = (const float*)d_in[6];
  const float* sigma   = (const float*)d_in[7];
  float* out = (float*)d_out;

  float* ws = (float*)d_ws;
  float* qtheta = ws;                          // BN*8        = 262144
  float* phiT   = qtheta + (size_t)BN * 8;     // 2*M*8       = 65536
  float* gp     = phiT + (size_t)2 * NPOOL * 8;    // 2*M*64  = 524288
  float* part_l = gp + (size_t)2 * NPOOL * 64;     // NCHUNK*BN = 131072
  float* part_o = part_l + (size_t)NCHUNK * BN;    // NCHUNK*BN*64 = 8388608
  // total ~ 37.5 MB of workspace

  theta_kernel<<<BN / 256, 256, 0, stream>>>(x, w_theta, b_theta, qtheta);
  pool_kernel<<<128, 256, 0, stream>>>(x, w_phi, b_phi, w_g, b_g, phiT, gp);
  attn_kernel<<<dim3(128, NCHUNK), 256, 0, stream>>>(qtheta, phiT, gp, part_l, part_o);
  reduce_kernel<<<BN / 256, 256, 0, stream>>>(part_l, part_o, x, sigma, out);
}

// Round 4
// 144.816 us; speedup vs baseline: 4.2350x; 4.2350x over previous
//
#include <hip/hip_runtime.h>
#include <hip/hip_bf16.h>

typedef _Float16 half8 __attribute__((ext_vector_type(8)));
typedef float f32x16 __attribute__((ext_vector_type(16)));

#define NPIX 16384      // H*W
#define NPOOL 4096      // pooled N
#define BN 32768        // B*NPIX
#define KSPLIT 4
#define LOG2E 1.44269504088896340736f

__device__ inline f32x16 mfma16(half8 a, half8 b, f32x16 c) {
  return __builtin_amdgcn_mfma_f32_32x32x16_f16(a, b, c, 0, 0, 0);
}

// ---------------- K1: theta -> Q f16 [BN][8], scaled by log2(e) ----------------
__global__ __launch_bounds__(256) void theta_kernel(
    const float* __restrict__ x, const float* __restrict__ w,
    const float* __restrict__ bias, _Float16* __restrict__ qf) {
  int idx = blockIdx.x * 256 + threadIdx.x;
  int b = idx >> 14, n = idx & (NPIX - 1);
  const float* xb = x + (size_t)b * 64 * NPIX + n;
  float acc[8];
#pragma unroll
  for (int j = 0; j < 8; j++) acc[j] = bias[j];
  for (int c = 0; c < 64; c++) {
    float xv = xb[(size_t)c * NPIX];
#pragma unroll
    for (int j = 0; j < 8; j++) acc[j] += xv * w[j * 64 + c];
  }
  half8 h;
#pragma unroll
  for (int j = 0; j < 8; j++) h[j] = (_Float16)(acc[j] * LOG2E);
  *(half8*)(qf + (size_t)idx * 8) = h;
}

// ------- K2: phiT f16 [b][M][8], gT f16 [b][64][M] = maxpool2(conv1x1) --------
__global__ __launch_bounds__(256) void pool_kernel(
    const float* __restrict__ x,
    const float* __restrict__ w_phi, const float* __restrict__ b_phi,
    const float* __restrict__ w_g, const float* __restrict__ b_g,
    _Float16* __restrict__ phiT, _Float16* __restrict__ gT) {
  __shared__ float xs[64][256];
  int bid = blockIdx.x;
  int b = bid >> 6, pr = bid & 63;
  const float* xb = x + (size_t)b * 64 * NPIX + pr * 256;
  int t = threadIdx.x;
  for (int c = 0; c < 64; c++) xs[c][t] = xb[(size_t)c * NPIX + t];
  __syncthreads();
#pragma unroll 1
  for (int iter = 0; iter < 18; iter++) {
    int out_i = iter * 256 + t;
    int oc = out_i >> 6;
    int pos = out_i & 63;
    const float* wrow;
    float bv;
    if (oc < 64) { wrow = w_g + oc * 64; bv = b_g[oc]; }
    else         { wrow = w_phi + (oc - 64) * 64; bv = b_phi[oc - 64]; }
    float a0 = bv, a1 = bv, a2 = bv, a3 = bv;
    int p0 = pos * 2;
    for (int c = 0; c < 64; c++) {
      float wv = wrow[c];
      a0 += wv * xs[c][p0];
      a1 += wv * xs[c][p0 + 1];
      a2 += wv * xs[c][p0 + 128];
      a3 += wv * xs[c][p0 + 129];
    }
    float v = fmaxf(fmaxf(a0, a1), fmaxf(a2, a3));
    int m = pr * 64 + pos;
    if (oc < 64) gT[((size_t)b * 64 + oc) * NPOOL + m] = (_Float16)v;
    else         phiT[((size_t)b * NPOOL + m) * 8 + (oc - 64)] = (_Float16)v;
  }
}

// ---------------- K2b: per-query score max (log2 units) ----------------
// block = 4 waves x 32 queries; grid = b(2) x qtile(128)
__global__ __launch_bounds__(256, 4) void qmax_kernel(
    const _Float16* __restrict__ qf, const _Float16* __restrict__ phiT,
    float* __restrict__ qmax) {
  int bx = blockIdx.x;
  int qt = bx & 127, b = bx >> 7;
  int tid = threadIdx.x;
  int w = tid >> 6, lane = tid & 63;
  int q = lane & 31, hi = lane >> 5;
  int qg0 = qt * 128 + w * 32;

  half8 qfrag = {0, 0, 0, 0, 0, 0, 0, 0};
  if (!hi) qfrag = *(const half8*)(qf + ((size_t)b * NPIX + qg0 + q) * 8);
  float m = -3e38f;
  for (int kb = 0; kb < NPOOL; kb += 32) {
    half8 aphi = {0, 0, 0, 0, 0, 0, 0, 0};
    if (!hi) aphi = *(const half8*)(phiT + ((size_t)b * NPOOL + kb + q) * 8);
    f32x16 sacc;
#pragma unroll
    for (int i = 0; i < 16; i++) sacc[i] = 0.f;
    sacc = mfma16(aphi, qfrag, sacc);
#pragma unroll
    for (int i = 0; i < 16; i++) m = fmaxf(m, sacc[i]);
  }
  m = fmaxf(m, __shfl_xor(m, 32));
  if (!hi) qmax[(size_t)b * NPIX + qg0 + q] = m;
}

// ---------------- K3: MFMA flash attention partials (exact softmax) ----------------
// block = 4 waves x 32 queries; grid = b(2) x qtile(128) x kc(4)
__global__ __launch_bounds__(256, 4) void attn_kernel(
    const _Float16* __restrict__ qf, const _Float16* __restrict__ phiT,
    const _Float16* __restrict__ gT, const float* __restrict__ qmax,
    float* __restrict__ part_l, float* __restrict__ part_o) {
  __shared__ _Float16 lds_g[64 * 64];    // [c row][64 keys], XOR-swizzled 16B slots
  int bx = blockIdx.x;
  int kc = bx & (KSPLIT - 1);
  int qt = (bx >> 2) & 127;
  int b  = bx >> 9;
  int tid = threadIdx.x;
  int w = tid >> 6, lane = tid & 63;
  int q = lane & 31, hi = lane >> 5;
  int qg0 = qt * 128 + w * 32;

  half8 qfrag = {0, 0, 0, 0, 0, 0, 0, 0};
  if (!hi) qfrag = *(const half8*)(qf + ((size_t)b * NPIX + qg0 + q) * 8);
  float mqv = qmax[(size_t)b * NPIX + qg0 + q];   // per-lane uniform shift

  f32x16 oacc0, oacc1;
#pragma unroll
  for (int i = 0; i < 16; i++) { oacc0[i] = 0.f; oacc1[i] = 0.f; }
  float lsum = 0.f;

  int kb0 = kc * (NPOOL / KSPLIT);
  for (int step = 0; step < (NPOOL / KSPLIT) / 64; ++step) {
    int kb = kb0 + step * 64;
    __syncthreads();
#pragma unroll
    for (int h = 0; h < 2; ++h) {
      int ch = tid + h * 256;
      int c = ch >> 3, s = ch & 7;
      half8 v = *(const half8*)(gT + ((size_t)b * 64 + c) * NPOOL + kb + 8 * s);
      *(half8*)(lds_g + c * 64 + ((((16 * s) ^ ((c & 7) << 4))) >> 1)) = v;
    }
    __syncthreads();
#pragma unroll
    for (int sub = 0; sub < 2; ++sub) {
      half8 aphi = {0, 0, 0, 0, 0, 0, 0, 0};
      if (!hi) aphi = *(const half8*)(phiT + ((size_t)b * NPOOL + kb + sub * 32 + q) * 8);
      f32x16 sacc;
#pragma unroll
      for (int i = 0; i < 16; i++) sacc[i] = -mqv;   // exact per-query shift
      sacc = mfma16(aphi, qfrag, sacc);
      float p[16];
#pragma unroll
      for (int i = 0; i < 16; i++) {
        p[i] = exp2f(sacc[i]);                       // in (0, 1]
        lsum += p[i];
      }
#pragma unroll
      for (int halfk = 0; halfk < 2; ++halfk) {
        int pb = halfk * 8;
        unsigned A0 = __builtin_bit_cast(unsigned, __builtin_amdgcn_cvt_pkrtz(p[pb + 0], p[pb + 1]));
        unsigned A1 = __builtin_bit_cast(unsigned, __builtin_amdgcn_cvt_pkrtz(p[pb + 2], p[pb + 3]));
        unsigned B0 = __builtin_bit_cast(unsigned, __builtin_amdgcn_cvt_pkrtz(p[pb + 4], p[pb + 5]));
        unsigned B1 = __builtin_bit_cast(unsigned, __builtin_amdgcn_cvt_pkrtz(p[pb + 6], p[pb + 7]));
        unsigned xA0 = __shfl_xor(A0, 32), xA1 = __shfl_xor(A1, 32);
        unsigned xB0 = __shfl_xor(B0, 32), xB1 = __shfl_xor(B1, 32);
        union { unsigned u[4]; half8 h; } pf;
        pf.u[0] = hi ? xB0 : A0;
        pf.u[1] = hi ? xB1 : A1;
        pf.u[2] = hi ? B0 : xA0;
        pf.u[3] = hi ? B1 : xA1;
        int sread = sub * 4 + halfk * 2 + hi;
#pragma unroll
        for (int ct = 0; ct < 2; ++ct) {
          int row = ct * 32 + q;
          half8 ag = *(const half8*)(lds_g + row * 64 +
                                     (((16 * sread) ^ ((row & 7) << 4)) >> 1));
          if (ct == 0) oacc0 = mfma16(ag, pf.h, oacc0);
          else         oacc1 = mfma16(ag, pf.h, oacc1);
        }
      }
    }
  }
  lsum += __shfl_xor(lsum, 32);
  if (!hi) part_l[(size_t)kc * BN + b * NPIX + qg0 + q] = lsum;
  float* po = part_o + ((size_t)(kc * 2 + b) * 64) * NPIX + qg0 + q;
#pragma unroll
  for (int ct = 0; ct < 2; ++ct)
#pragma unroll
    for (int r = 0; r < 16; ++r) {
      int c = (r & 3) + 8 * (r >> 2) + 4 * hi + 32 * ct;
      po[(size_t)c * NPIX] = (ct ? oacc1[r] : oacc0[r]);
    }
}

// ---------------- K4: combine K-split partials + residual epilogue ----------------
__global__ __launch_bounds__(256) void reduce_kernel(
    const float* __restrict__ part_l, const float* __restrict__ part_o,
    const float* __restrict__ x, const float* __restrict__ sig,
    float* __restrict__ out) {
  size_t i4 = ((size_t)blockIdx.x * 256 + threadIdx.x) * 4;
  int b = (int)(i4 >> 20);
  int c = (int)((i4 >> 14) & 63);
  int n = (int)(i4 & 16383);
  float o0 = 0, o1 = 0, o2 = 0, o3 = 0;
  float l0 = 0, l1 = 0, l2 = 0, l3 = 0;
#pragma unroll
  for (int kc = 0; kc < KSPLIT; kc++) {
    const float* po = part_o + ((size_t)(kc * 2 + b) * 64 + c) * NPIX + n;
    float4 v = *(const float4*)po;
    o0 += v.x; o1 += v.y; o2 += v.z; o3 += v.w;
    const float* pl = part_l + (size_t)kc * BN + b * NPIX + n;
    float4 lv = *(const float4*)pl;
    l0 += lv.x; l1 += lv.y; l2 += lv.z; l3 += lv.w;
  }
  float s0 = sig[0];
  float4 xv = *(const float4*)(x + i4);
  float4 r;
  r.x = xv.x + s0 * o0 / l0;
  r.y = xv.y + s0 * o1 / l1;
  r.z = xv.z + s0 * o2 / l2;
  r.w = xv.w + s0 * o3 / l3;
  *(float4*)(((float*)out) + i4) = r;
}

extern "C" void kernel_launch(void* const* d_in, const int* in_sizes, int n_in,
                              void* d_out, int out_size, void* d_ws, size_t ws_size,
                              hipStream_t stream) {
  const float* x       = (const float*)d_in[0];
  const float* w_theta = (const float*)d_in[1];
  const float* b_theta = (const float*)d_in[2];
  const float* w_phi   = (const float*)d_in[3];
  const float* b_phi   = (const float*)d_in[4];
  const float* w_g     = (const float*)d_in[5];
  const float* b_g     = (const float*)d_in[6];
  const float* sigma   = (const float*)d_in[7];
  float* out = (float*)d_out;

  // Workspace layout (bytes):
  //   qf     @ 0        : BN*8*2           = 524288
  //   phiT   @ 524288   : 2*NPOOL*8*2      = 131072
  //   gT     @ 655360   : 2*64*NPOOL*2     = 1048576
  //   qmax   @ 1703936  : BN*4             = 131072
  //   part_l @ 1835008  : KSPLIT*BN*4      = 524288   (round-3 bug: was 128KB gap)
  //   part_o @ 2359296  : KSPLIT*2*64*NPIX*4 = 33554432
  char* ws = (char*)d_ws;
  _Float16* qf   = (_Float16*)ws;
  _Float16* phiT = (_Float16*)(ws + 524288);
  _Float16* gT   = (_Float16*)(ws + 655360);
  float* qmax    = (float*)(ws + 1703936);
  float* part_l  = (float*)(ws + 1835008);
  float* part_o  = (float*)(ws + 2359296);

  theta_kernel<<<BN / 256, 256, 0, stream>>>(x, w_theta, b_theta, qf);
  pool_kernel<<<128, 256, 0, stream>>>(x, w_phi, b_phi, w_g, b_g, phiT, gT);
  qmax_kernel<<<256, 256, 0, stream>>>(qf, phiT, qmax);
  attn_kernel<<<2 * 128 * KSPLIT, 256, 0, stream>>>(qf, phiT, gT, qmax, part_l, part_o);
  reduce_kernel<<<2048, 256, 0, stream>>>(part_l, part_o, x, sigma, out);
}

// Round 6
// 113.938 us; speedup vs baseline: 5.3826x; 1.2710x over previous
//
#include <hip/hip_runtime.h>
#include <hip/hip_bf16.h>

typedef _Float16 half8 __attribute__((ext_vector_type(8)));
typedef __fp16 fp16x2 __attribute__((ext_vector_type(2)));
typedef float f32x16 __attribute__((ext_vector_type(16)));

#define NPIX 16384      // H*W
#define NPOOL 4096      // pooled N
#define BN 32768        // B*N
#define KSPLIT 4
#define LOG2E 1.44269504088896340736f

__device__ inline f32x16 mfma16(half8 a, half8 b, f32x16 c) {
  return __builtin_amdgcn_mfma_f32_32x32x16_f16(a, b, c, 0, 0, 0);
}

// ---- K1 (fused prep): theta f16 [BN][8]*log2e; phiT f16 [b][M][8]; gT f16 [b][64][M]
// grid = b(2) x pr(64) x ochalf(2) = 256 blocks, 256 threads, 64 KB LDS.
__global__ __launch_bounds__(256) void prep_kernel(
    const float* __restrict__ x,
    const float* __restrict__ w_theta, const float* __restrict__ b_theta,
    const float* __restrict__ w_phi, const float* __restrict__ b_phi,
    const float* __restrict__ w_g, const float* __restrict__ b_g,
    _Float16* __restrict__ qf, _Float16* __restrict__ phiT,
    _Float16* __restrict__ gT) {
  __shared__ float xs[64][256];
  int bid = blockIdx.x;
  int oh = bid & 1;
  int pr = (bid >> 1) & 63;
  int b  = bid >> 7;
  int t = threadIdx.x;

  const float* xb = x + (size_t)b * 64 * NPIX + pr * 256;
#pragma unroll 8
  for (int c = 0; c < 64; c++) xs[c][t] = xb[(size_t)c * NPIX + t];
  __syncthreads();

  if (oh == 0) {
    // ---- theta: pixel = t ----
    float acc[8];
#pragma unroll
    for (int j = 0; j < 8; j++) acc[j] = b_theta[j];
    for (int c = 0; c < 64; c++) {
      float xv = xs[c][t];
#pragma unroll
      for (int j = 0; j < 8; j++) acc[j] += xv * w_theta[j * 64 + c];
    }
    half8 h;
#pragma unroll
    for (int j = 0; j < 8; j++) h[j] = (_Float16)(acc[j] * LOG2E);
    *(half8*)(qf + ((size_t)b * NPIX + pr * 256 + t) * 8) = h;
  }

  // ---- pooled convs: pos = t&63, 9 channels per thread ----
  int pos = t & 63;
  int ocg = t >> 6;                      // wave-uniform
  int oc0 = oh * 36 + ocg * 9;           // first of 9 channels
  const float* wrow[9];
  float a0[9], a1[9], a2[9], a3[9];
#pragma unroll
  for (int j = 0; j < 9; j++) {
    int oc = oc0 + j;
    float bv;
    if (oc < 64) { wrow[j] = w_g + oc * 64; bv = b_g[oc]; }
    else         { wrow[j] = w_phi + (oc - 64) * 64; bv = b_phi[oc - 64]; }
    a0[j] = bv; a1[j] = bv; a2[j] = bv; a3[j] = bv;
  }
  for (int c = 0; c < 64; c++) {
    float2 lo = *(const float2*)&xs[c][2 * pos];
    float2 hi = *(const float2*)&xs[c][128 + 2 * pos];
#pragma unroll
    for (int j = 0; j < 9; j++) {
      float wv = wrow[j][c];             // wave-uniform -> scalar load
      a0[j] += wv * lo.x;
      a1[j] += wv * lo.y;
      a2[j] += wv * hi.x;
      a3[j] += wv * hi.y;
    }
  }
  int m = pr * 64 + pos;
#pragma unroll
  for (int j = 0; j < 9; j++) {
    int oc = oc0 + j;
    float v = fmaxf(fmaxf(a0[j], a1[j]), fmaxf(a2[j], a3[j]));
    if (oc < 64) gT[((size_t)b * 64 + oc) * NPOOL + m] = (_Float16)v;
    else         phiT[((size_t)b * NPOOL + m) * 8 + (oc - 64)] = (_Float16)v;
  }
}

// ---------------- K2b: per-query score max (log2 units) ----------------
__global__ __launch_bounds__(256, 4) void qmax_kernel(
    const _Float16* __restrict__ qf, const _Float16* __restrict__ phiT,
    float* __restrict__ qmax) {
  int bx = blockIdx.x;
  int qt = bx & 127, b = bx >> 7;
  int tid = threadIdx.x;
  int w = tid >> 6, lane = tid & 63;
  int q = lane & 31, hi = lane >> 5;
  int qg0 = qt * 128 + w * 32;

  half8 qfrag = {0, 0, 0, 0, 0, 0, 0, 0};
  if (!hi) qfrag = *(const half8*)(qf + ((size_t)b * NPIX + qg0 + q) * 8);
  float m = -3e38f;
  for (int kb = 0; kb < NPOOL; kb += 32) {
    half8 aphi = {0, 0, 0, 0, 0, 0, 0, 0};
    if (!hi) aphi = *(const half8*)(phiT + ((size_t)b * NPOOL + kb + q) * 8);
    f32x16 sacc;
#pragma unroll
    for (int i = 0; i < 16; i++) sacc[i] = 0.f;
    sacc = mfma16(aphi, qfrag, sacc);
#pragma unroll
    for (int i = 0; i < 16; i++) m = fmaxf(m, sacc[i]);
  }
  m = fmaxf(m, __shfl_xor(m, 32));
  if (!hi) qmax[(size_t)b * NPIX + qg0 + q] = m;
}

// ---------------- K3: MFMA flash attention partials (exact softmax) ----------------
__global__ __launch_bounds__(256, 4) void attn_kernel(
    const _Float16* __restrict__ qf, const _Float16* __restrict__ phiT,
    const _Float16* __restrict__ gT, const float* __restrict__ qmax,
    float* __restrict__ part_l, float* __restrict__ part_o) {
  __shared__ _Float16 lds_g[64 * 64];    // [c row][64 keys], XOR-swizzled 16B slots
  int bx = blockIdx.x;
  int kc = bx & (KSPLIT - 1);
  int qt = (bx >> 2) & 127;
  int b  = bx >> 9;
  int tid = threadIdx.x;
  int w = tid >> 6, lane = tid & 63;
  int q = lane & 31, hi = lane >> 5;
  int qg0 = qt * 128 + w * 32;

  half8 qfrag = {0, 0, 0, 0, 0, 0, 0, 0};
  if (!hi) qfrag = *(const half8*)(qf + ((size_t)b * NPIX + qg0 + q) * 8);
  float mqv = qmax[(size_t)b * NPIX + qg0 + q];   // per-lane uniform shift

  f32x16 oacc0, oacc1;
#pragma unroll
  for (int i = 0; i < 16; i++) { oacc0[i] = 0.f; oacc1[i] = 0.f; }
  float lsum = 0.f;

  int kb0 = kc * (NPOOL / KSPLIT);
  for (int step = 0; step < (NPOOL / KSPLIT) / 64; ++step) {
    int kb = kb0 + step * 64;
    __syncthreads();
#pragma unroll
    for (int h = 0; h < 2; ++h) {
      int ch = tid + h * 256;
      int c = ch >> 3, s = ch & 7;
      half8 v = *(const half8*)(gT + ((size_t)b * 64 + c) * NPOOL + kb + 8 * s);
      *(half8*)(lds_g + c * 64 + ((((16 * s) ^ ((c & 7) << 4))) >> 1)) = v;
    }
    __syncthreads();
#pragma unroll
    for (int sub = 0; sub < 2; ++sub) {
      half8 aphi = {0, 0, 0, 0, 0, 0, 0, 0};
      if (!hi) aphi = *(const half8*)(phiT + ((size_t)b * NPOOL + kb + sub * 32 + q) * 8);
      f32x16 sacc;
#pragma unroll
      for (int i = 0; i < 16; i++) sacc[i] = -mqv;   // exact per-query shift
      sacc = mfma16(aphi, qfrag, sacc);
      float p[16];
#pragma unroll
      for (int i = 0; i < 16; i++) p[i] = exp2f(sacc[i]);   // in (0, 1]
#pragma unroll
      for (int halfk = 0; halfk < 2; ++halfk) {
        int pb = halfk * 8;
        fp16x2 h0 = __builtin_amdgcn_cvt_pkrtz(p[pb + 0], p[pb + 1]);
        fp16x2 h1 = __builtin_amdgcn_cvt_pkrtz(p[pb + 2], p[pb + 3]);
        fp16x2 h2 = __builtin_amdgcn_cvt_pkrtz(p[pb + 4], p[pb + 5]);
        fp16x2 h3 = __builtin_amdgcn_cvt_pkrtz(p[pb + 6], p[pb + 7]);
#if __has_builtin(__builtin_amdgcn_fdot2)
        const fp16x2 ones = {(__fp16)1.0f, (__fp16)1.0f};
        lsum = __builtin_amdgcn_fdot2(h0, ones, lsum, false);
        lsum = __builtin_amdgcn_fdot2(h1, ones, lsum, false);
        lsum = __builtin_amdgcn_fdot2(h2, ones, lsum, false);
        lsum = __builtin_amdgcn_fdot2(h3, ones, lsum, false);
#else
        lsum += p[pb + 0] + p[pb + 1] + p[pb + 2] + p[pb + 3];
        lsum += p[pb + 4] + p[pb + 5] + p[pb + 6] + p[pb + 7];
#endif
        unsigned A0 = __builtin_bit_cast(unsigned, h0);
        unsigned A1 = __builtin_bit_cast(unsigned, h1);
        unsigned B0 = __builtin_bit_cast(unsigned, h2);
        unsigned B1 = __builtin_bit_cast(unsigned, h3);
        unsigned xA0 = __shfl_xor(A0, 32), xA1 = __shfl_xor(A1, 32);
        unsigned xB0 = __shfl_xor(B0, 32), xB1 = __shfl_xor(B1, 32);
        union { unsigned u[4]; half8 h; } pf;
        pf.u[0] = hi ? xB0 : A0;
        pf.u[1] = hi ? xB1 : A1;
        pf.u[2] = hi ? B0 : xA0;
        pf.u[3] = hi ? B1 : xA1;
        int sread = sub * 4 + halfk * 2 + hi;
#pragma unroll
        for (int ct = 0; ct < 2; ++ct) {
          int row = ct * 32 + q;
          half8 ag = *(const half8*)(lds_g + row * 64 +
                                     (((16 * sread) ^ ((row & 7) << 4)) >> 1));
          if (ct == 0) oacc0 = mfma16(ag, pf.h, oacc0);
          else         oacc1 = mfma16(ag, pf.h, oacc1);
        }
      }
    }
  }
  lsum += __shfl_xor(lsum, 32);
  if (!hi) part_l[(size_t)kc * BN + b * NPIX + qg0 + q] = lsum;
  float* po = part_o + ((size_t)(kc * 2 + b) * 64) * NPIX + qg0 + q;
#pragma unroll
  for (int ct = 0; ct < 2; ++ct)
#pragma unroll
    for (int r = 0; r < 16; ++r) {
      int c = (r & 3) + 8 * (r >> 2) + 4 * hi + 32 * ct;
      po[(size_t)c * NPIX] = (ct ? oacc1[r] : oacc0[r]);
    }
}

// ---------------- K4: combine K-split partials + residual epilogue ----------------
__global__ __launch_bounds__(256) void reduce_kernel(
    const float* __restrict__ part_l, const float* __restrict__ part_o,
    const float* __restrict__ x, const float* __restrict__ sig,
    float* __restrict__ out) {
  size_t i4 = ((size_t)blockIdx.x * 256 + threadIdx.x) * 4;
  int b = (int)(i4 >> 20);
  int c = (int)((i4 >> 14) & 63);
  int n = (int)(i4 & 16383);
  float o0 = 0, o1 = 0, o2 = 0, o3 = 0;
  float l0 = 0, l1 = 0, l2 = 0, l3 = 0;
#pragma unroll
  for (int kc = 0; kc < KSPLIT; kc++) {
    const float* po = part_o + ((size_t)(kc * 2 + b) * 64 + c) * NPIX + n;
    float4 v = *(const float4*)po;
    o0 += v.x; o1 += v.y; o2 += v.z; o3 += v.w;
    const float* pl = part_l + (size_t)kc * BN + b * NPIX + n;
    float4 lv = *(const float4*)pl;
    l0 += lv.x; l1 += lv.y; l2 += lv.z; l3 += lv.w;
  }
  float s0 = sig[0];
  float4 xv = *(const float4*)(x + i4);
  float4 r;
  r.x = xv.x + s0 * o0 / l0;
  r.y = xv.y + s0 * o1 / l1;
  r.z = xv.z + s0 * o2 / l2;
  r.w = xv.w + s0 * o3 / l3;
  *(float4*)(((float*)out) + i4) = r;
}

extern "C" void kernel_launch(void* const* d_in, const int* in_sizes, int n_in,
                              void* d_out, int out_size, void* d_ws, size_t ws_size,
                              hipStream_t stream) {
  const float* x       = (const float*)d_in[0];
  const float* w_theta = (const float*)d_in[1];
  const float* b_theta = (const float*)d_in[2];
  const float* w_phi   = (const float*)d_in[3];
  const float* b_phi   = (const float*)d_in[4];
  const float* w_g     = (const float*)d_in[5];
  const float* b_g     = (const float*)d_in[6];
  const float* sigma   = (const float*)d_in[7];
  float* out = (float*)d_out;

  // Workspace layout (bytes):
  //   qf     @ 0        : BN*8*2             = 524288
  //   phiT   @ 524288   : 2*NPOOL*8*2        = 131072
  //   gT     @ 655360   : 2*64*NPOOL*2       = 1048576
  //   qmax   @ 1703936  : BN*4               = 131072
  //   part_l @ 1835008  : KSPLIT*BN*4        = 524288
  //   part_o @ 2359296  : KSPLIT*2*64*NPIX*4 = 33554432
  char* ws = (char*)d_ws;
  _Float16* qf   = (_Float16*)ws;
  _Float16* phiT = (_Float16*)(ws + 524288);
  _Float16* gT   = (_Float16*)(ws + 655360);
  float* qmax    = (float*)(ws + 1703936);
  float* part_l  = (float*)(ws + 1835008);
  float* part_o  = (float*)(ws + 2359296);

  prep_kernel<<<256, 256, 0, stream>>>(x, w_theta, b_theta, w_phi, b_phi,
                                       w_g, b_g, qf, phiT, gT);
  qmax_kernel<<<256, 256, 0, stream>>>(qf, phiT, qmax);
  attn_kernel<<<2 * 128 * KSPLIT, 256, 0, stream>>>(qf, phiT, gT, qmax, part_l, part_o);
  reduce_kernel<<<2048, 256, 0, stream>>>(part_l, part_o, x, sigma, out);
}